// Round 5
// baseline (168.870 us; speedup 1.0000x reference)
//
#include <hip/hip_runtime.h>

#define BATCH 50
#define NATOMS 512
#define NBONDS 4096
#define NXF (NATOMS*3)            // floats of x per batch = 1536 (6 KB)
#define BPB (NBONDS/256)          // bond blocks per batch = 16
#define BITS_W (NATOMS*NATOMS/32) // ownership bitmask words per batch = 8192

__device__ __forceinline__ float sigmoidf_(float x){ return 1.f/(1.f+__expf(-x)); }

// exact transcription of reference _taper
__device__ __forceinline__ float taperf_(float r, float rmin, float rmax){
    float r3  = (r > rmax) ? 1.f : 0.f;
    bool  ok  = (r <= rmax) && (r > rmin);
    float r2  = ok ? r   : 0.f;
    float r20 = ok ? 1.f : 0.f;
    float d   = rmin - rmax;
    float rterm = 1.f/(d*d*d);
    float rm  = rmin*r20;
    float rd  = rm - r2;
    float trm1 = rm + 2.f*r2 - 3.f*rmax*r20;
    return rterm*rd*rd*trm1 + r3;
}

// One fused kernel: bond phase (all blocks) + atom phase (last-finishing block
// per batch). Pair ownership via zero-initialized bit table: first atomicOr
// wins; duplicates carry bit-identical values so count-once is exact.
// MLP weights staged in LDS, TRANSPOSED to [l][u][v]; layer loop FULLY
// unrolled so the compiler can software-pipeline all weight ds_reads ahead
// of their consumers (R0 evidence: latency-bound kernel wants straight-line
// code + fat registers, not bounded unroll).
__global__ __launch_bounds__(256) void fused_kernel(
    const float* __restrict__ x, const float* __restrict__ cell, const float* __restrict__ rcell,
    const float* __restrict__ sp_p, const float* __restrict__ gp, const float* __restrict__ bp,
    const float* __restrict__ fe_wi, const float* __restrict__ fe_w, const float* __restrict__ fe_b,
    const float* __restrict__ fe_wo, const float* __restrict__ fe_bo,
    const int* __restrict__ bdid, const int* __restrict__ spec,
    float* __restrict__ Delta, float* __restrict__ Delta_pi, float* __restrict__ SO,
    float* __restrict__ ebond_acc, unsigned* __restrict__ done, unsigned* __restrict__ bits,
    float* __restrict__ out)
{
    __shared__ float s_x[NXF];                       // 6 KB coordinates
    __shared__ __align__(16) float s_w[320];         // [l][u][v] transposed
    __shared__ __align__(16) float s_wo[8];
    __shared__ float s_wi[24], s_bb[40];
    __shared__ float s_part[4];
    __shared__ unsigned s_rank;
    int tid = threadIdx.x;
    int b   = blockIdx.y;

    // coalesced float4 stage of x[b] into LDS (384 float4 / 256 threads)
    const float4* xb4 = (const float4*)(x + (size_t)b*NXF);
    float4* sx4 = (float4*)s_x;
    sx4[tid] = xb4[tid];
    if(tid < NXF/4 - 256) sx4[tid+256] = xb4[tid+256];
    // weights: transpose [l][v][u] -> [l][u][v] while staging.
    // LOOP, not a single predicate: 320 elements > 256 threads (R3 bug).
    for(int t=tid; t<320; t+=256){
        int l = t>>6, rr = t&63, v = rr>>3, u = rr&7;
        s_w[(l<<6) + (u<<3) + v] = fe_w[t];
    }
    if(tid < 24) s_wi[tid] = fe_wi[tid];
    if(tid < 40) s_bb[tid] = fe_b[tid];
    if(tid < 8)  s_wo[tid] = fe_wo[tid];
    __syncthreads();

    // wave-uniform params -> scalar loads (hoisted once, few values)
    float botol = gp[6];
    float rosi=bp[0], ropi=bp[1], ropp=bp[2];
    float bo1=bp[3], bo2=bp[4], bo3=bp[5], bo4=bp[6], bo5=bp[7], bo6=bp[8], Desi=bp[9];
    float bo_out = fe_bo[0];
    const float* cb = cell  + b*9;
    const float* rb = rcell + b*9;

    int k = blockIdx.x*256 + tid;            // NBONDS == gridDim.x*256 exactly
    int2 ij = ((const int2*)bdid)[k];
    int i = ij.x, j = ij.y;
    float dx0 = s_x[3*i+0]-s_x[3*j+0];
    float dx1 = s_x[3*i+1]-s_x[3*j+1];
    float dx2 = s_x[3*i+2]-s_x[3*j+2];
    // fractional coords, minimum image, back to cartesian
    float f0 = dx0*rb[0]+dx1*rb[3]+dx2*rb[6];
    float f1 = dx0*rb[1]+dx1*rb[4]+dx2*rb[7];
    float f2 = dx0*rb[2]+dx1*rb[5]+dx2*rb[8];
    f0 = (f0>0.5f)?f0-1.f:f0; f0 = (f0<-0.5f)?f0+1.f:f0;
    f1 = (f1>0.5f)?f1-1.f:f1; f1 = (f1<-0.5f)?f1+1.f:f1;
    f2 = (f2>0.5f)?f2-1.f:f2; f2 = (f2<-0.5f)?f2+1.f:f2;
    float v0 = f0*cb[0]+f1*cb[3]+f2*cb[6];
    float v1 = f0*cb[1]+f1*cb[4]+f2*cb[7];
    float v2 = f0*cb[2]+f1*cb[5]+f2*cb[8];
    float r = sqrtf(v0*v0+v1*v1+v2*v2);

    float eterm1 = (1.f+botol)*__expf(bo1*__powf(r/rosi, bo2));
    float eterm2 = __expf(bo3*__powf(r/ropi, bo4));
    float eterm3 = __expf(bo5*__powf(r/ropp, bo6));
    float tmax = 2.f*botol;
    float si = taperf_(eterm1, botol, tmax)*(eterm1-botol);
    float pi = taperf_(eterm2, botol, tmax)*eterm2;
    float pp = taperf_(eterm3, botol, tmax)*eterm3;

    // ---- MLP: 3 -> 8 -> (8x8)x5 -> 1, sigmoid everywhere ----
    float o[8];
    #pragma unroll
    for(int u=0;u<8;u++)
        o[u] = sigmoidf_(si*s_wi[u] + pi*s_wi[8+u] + pp*s_wi[16+u]);
    #pragma unroll
    for(int l=0;l<5;l++){
        const float4* wl = (const float4*)(s_w + (l<<6));
        const float*  bl = s_bb + (l<<3);
        float no[8];
        #pragma unroll
        for(int u=0;u<8;u++){
            float4 wa = wl[2*u], wb = wl[2*u+1];      // uniform ds_read_b128 x2
            float a0 = fmaf(o[0],wa.x, bl[u]);
            float a1 = o[1]*wa.y;
            a0 = fmaf(o[2],wa.z,a0); a1 = fmaf(o[3],wa.w,a1);
            a0 = fmaf(o[4],wb.x,a0); a1 = fmaf(o[5],wb.y,a1);
            a0 = fmaf(o[6],wb.z,a0); a1 = fmaf(o[7],wb.w,a1);
            no[u] = sigmoidf_(a0+a1);
        }
        #pragma unroll
        for(int u=0;u<8;u++) o[u]=no[u];
    }
    float4 woa = ((const float4*)s_wo)[0], wob = ((const float4*)s_wo)[1];
    float a0 = fmaf(o[0],woa.x, bo_out);
    float a1 = o[1]*woa.y;
    a0 = fmaf(o[2],woa.z,a0); a1 = fmaf(o[3],woa.w,a1);
    a0 = fmaf(o[4],wob.x,a0); a1 = fmaf(o[5],wob.y,a1);
    a0 = fmaf(o[6],wob.z,a0); a1 = fmaf(o[7],wob.w,a1);
    float esi = sigmoidf_(a0+a1);

    // per-atom scatter: first arrival on the (b,i,j) bit owns the pair
    {
        unsigned pidx = (unsigned)(i*NATOMS + j);
        unsigned old = atomicOr(&bits[(size_t)b*BITS_W + (pidx>>5)], 1u<<(pidx&31));
        if(((old>>(pidx&31)) & 1u) == 0u){
            float bop = si+pi+pp;
            float dpi = pi+pp;
            float* Db = Delta    + (size_t)b*NATOMS;
            float* Pb = Delta_pi + (size_t)b*NATOMS;
            float* Sb = SO       + (size_t)b*NATOMS;
            atomicAdd(&Db[i], bop); atomicAdd(&Db[j], bop);
            atomicAdd(&Pb[i], dpi); atomicAdd(&Pb[j], dpi);
            atomicAdd(&Sb[i], si);  atomicAdd(&Sb[j], si);
        }
    }

    // ebond partial: sum over ALL bonds (duplicates included)
    float ev = -Desi*esi;
    #pragma unroll
    for(int o2=32;o2>0;o2>>=1) ev += __shfl_down(ev, o2, 64);
    if((tid & 63) == 0) s_part[tid>>6] = ev;
    __syncthreads();
    if(tid==0) atomicAdd(&ebond_acc[b], s_part[0]+s_part[1]+s_part[2]+s_part[3]);

    // publish this block's writes, then take a completion ticket for batch b
    // (R2-proven protocol: threadfence + barrier + ticket)
    __threadfence();
    __syncthreads();
    if(tid==0) s_rank = atomicAdd(&done[b], 1u);
    __syncthreads();
    if(s_rank != BPB-1) return;

    // ---- tail block (last to finish for this batch): atom phase ----
    float lp1=gp[0], ovun3=gp[1], ovun4=gp[2], ovun6=gp[3], ovun7=gp[4], ovun8=gp[5];
    float acc = 0.f;
    for(int n=tid; n<NATOMS; n+=256){
        int s = spec[n];
        const float* pa = sp_p + s*5;
        float val=pa[0], vale=pa[1], lp2=pa[2], ovun2=pa[3], ovun5=pa[4];
        size_t idx = (size_t)b*NATOMS + n;
        // agent-scope atomic loads: read through the coherent point, no stale L1
        float D   = __hip_atomic_load(&Delta[idx],    __ATOMIC_RELAXED, __HIP_MEMORY_SCOPE_AGENT);
        float Dpi = __hip_atomic_load(&Delta_pi[idx], __ATOMIC_RELAXED, __HIP_MEMORY_SCOPE_AGENT);
        float so  = __hip_atomic_load(&SO[idx],       __ATOMIC_RELAXED, __HIP_MEMORY_SCOPE_AGENT);

        float Nlp = 0.5f*(vale-val);
        float de  = 0.5f*(D-vale);
        float De  = fminf(ceilf(de), 0.f);          // -relu(-ceil(x)) == min(ceil(x),0)
        float t   = 1.f + de - De;
        float nlp = -De + __expf(-lp1*4.f*t*t);
        float Dlp = fmaxf(Nlp - nlp + 1.f, 0.f) - 1.f;
        float Elone = lp2*Dlp/(1.f+__expf(-75.f*Dlp));
        float dlp = D - val - Dlp/(1.f + ovun3*__expf(ovun4*Dpi));
        float denom = dlp + val;
        float otrm1 = 1.f/((denom!=0.f)?denom:1e-8f);
        float Eover = so*otrm1*dlp*sigmoidf_(-ovun2*dlp);
        float Eunder = -ovun5*(1.f-__expf(ovun6*dlp))*sigmoidf_(ovun2*dlp)
                       /(1.f + ovun7*__expf(ovun8*Dpi));
        acc += Elone + Eover + Eunder;
    }
    #pragma unroll
    for(int o2=32;o2>0;o2>>=1) acc += __shfl_down(acc, o2, 64);
    __syncthreads();                          // s_part reuse
    if((tid & 63) == 0) s_part[tid>>6] = acc;
    __syncthreads();
    if(tid==0){
        float eb = __hip_atomic_load(&ebond_acc[b], __ATOMIC_RELAXED, __HIP_MEMORY_SCOPE_AGENT);
        out[b] = eb + s_part[0]+s_part[1]+s_part[2]+s_part[3];   // sole writer
    }
}

extern "C" void kernel_launch(void* const* d_in, const int* in_sizes, int n_in,
                              void* d_out, int out_size, void* d_ws, size_t ws_size,
                              hipStream_t stream)
{
    const float* x     = (const float*)d_in[0];
    const float* cell  = (const float*)d_in[1];
    const float* rcell = (const float*)d_in[2];
    const float* sp_p  = (const float*)d_in[3];
    const float* gp    = (const float*)d_in[4];
    const float* bp    = (const float*)d_in[5];
    const float* fe_wi = (const float*)d_in[6];
    const float* fe_w  = (const float*)d_in[7];
    const float* fe_b  = (const float*)d_in[8];
    const float* fe_wo = (const float*)d_in[9];
    const float* fe_bo = (const float*)d_in[10];
    const int*   bdid  = (const int*)d_in[11];
    const int*   spec  = (const int*)d_in[12];
    float* out = (float*)d_out;

    // ws layout (contiguous, one memset):
    // Delta | Delta_pi | SO | ebond_acc | done | ownership bits
    float* Delta     = (float*)d_ws;
    float* Delta_pi  = Delta + BATCH*NATOMS;
    float* SO        = Delta_pi + BATCH*NATOMS;
    float* ebond_acc = SO + BATCH*NATOMS;
    unsigned* done   = (unsigned*)(ebond_acc + BATCH);
    unsigned* bits   = done + BATCH;

    size_t zbytes = (size_t)(3*BATCH*NATOMS + BATCH)*sizeof(float)
                  + (size_t)BATCH*sizeof(unsigned)
                  + (size_t)BATCH*BITS_W*sizeof(unsigned);
    hipMemsetAsync(d_ws, 0, zbytes, stream);

    fused_kernel<<<dim3(BPB, BATCH), 256, 0, stream>>>(
        x, cell, rcell, sp_p, gp, bp, fe_wi, fe_w, fe_b, fe_wo, fe_bo,
        bdid, spec, Delta, Delta_pi, SO, ebond_acc, done, bits, out);
}

// Round 6
// 135.837 us; speedup vs baseline: 1.2432x; 1.2432x over previous
//
#include <hip/hip_runtime.h>

#define BATCH 50
#define NATOMS 512
#define NBONDS 4096
#define NXF (NATOMS*3)            // floats of x per batch = 1536 (6 KB)
#define BPB (NBONDS/256)          // bond blocks per batch = 16
#define BITS_W (NATOMS*NATOMS/32) // ownership bitmask words per batch = 8192

__device__ __forceinline__ float sigmoidf_(float x){ return 1.f/(1.f+__expf(-x)); }

// exact transcription of reference _taper
__device__ __forceinline__ float taperf_(float r, float rmin, float rmax){
    float r3  = (r > rmax) ? 1.f : 0.f;
    bool  ok  = (r <= rmax) && (r > rmin);
    float r2  = ok ? r   : 0.f;
    float r20 = ok ? 1.f : 0.f;
    float d   = rmin - rmax;
    float rterm = 1.f/(d*d*d);
    float rm  = rmin*r20;
    float rd  = rm - r2;
    float trm1 = rm + 2.f*r2 - 3.f*rmax*r20;
    return rterm*rd*rd*trm1 + r3;
}

// One fused kernel: bond phase (all blocks) + atom phase (last-finishing block
// per batch). Pair ownership via zero-initialized bit table: first atomicOr
// wins; duplicates carry bit-identical values so count-once is exact.
//
// NO __threadfence(): all cross-block data (Delta/Delta_pi/SO/ebond/bits/done)
// is written with device-scope atomics, performed at the device coherence
// point. The __syncthreads() before the ticket drains vmcnt(0) (compiler
// emits full s_waitcnt before s_barrier), so this block's atomics are
// complete before the ticket is taken; tail reads with agent-scope atomic
// loads. The fence's L2-writeback (buffer_wbl2 x 800 blocks) is the
// suspected ~45us serializer (R2/R4/R5 all ~90us regardless of MLP codegen).
__global__ __launch_bounds__(256) void fused_kernel(
    const float* __restrict__ x, const float* __restrict__ cell, const float* __restrict__ rcell,
    const float* __restrict__ sp_p, const float* __restrict__ gp, const float* __restrict__ bp,
    const float* __restrict__ fe_wi, const float* __restrict__ fe_w, const float* __restrict__ fe_b,
    const float* __restrict__ fe_wo, const float* __restrict__ fe_bo,
    const int* __restrict__ bdid, const int* __restrict__ spec,
    float* __restrict__ Delta, float* __restrict__ Delta_pi, float* __restrict__ SO,
    float* __restrict__ ebond_acc, unsigned* __restrict__ done, unsigned* __restrict__ bits,
    float* __restrict__ out)
{
    __shared__ float s_x[NXF];                       // 6 KB coordinates
    __shared__ __align__(16) float s_w[320];         // [l][u][v] transposed
    __shared__ __align__(16) float s_wo[8];
    __shared__ float s_wi[24], s_bb[40];
    __shared__ float s_part[4];
    __shared__ unsigned s_rank;
    int tid = threadIdx.x;
    int b   = blockIdx.y;

    // coalesced float4 stage of x[b] into LDS (384 float4 / 256 threads)
    const float4* xb4 = (const float4*)(x + (size_t)b*NXF);
    float4* sx4 = (float4*)s_x;
    sx4[tid] = xb4[tid];
    if(tid < NXF/4 - 256) sx4[tid+256] = xb4[tid+256];
    // weights: transpose [l][v][u] -> [l][u][v] while staging.
    // LOOP, not a single predicate: 320 elements > 256 threads (R3 bug).
    for(int t=tid; t<320; t+=256){
        int l = t>>6, rr = t&63, v = rr>>3, u = rr&7;
        s_w[(l<<6) + (u<<3) + v] = fe_w[t];
    }
    if(tid < 24) s_wi[tid] = fe_wi[tid];
    if(tid < 40) s_bb[tid] = fe_b[tid];
    if(tid < 8)  s_wo[tid] = fe_wo[tid];
    __syncthreads();

    // wave-uniform params -> scalar loads (hoisted once, few values)
    float botol = gp[6];
    float rosi=bp[0], ropi=bp[1], ropp=bp[2];
    float bo1=bp[3], bo2=bp[4], bo3=bp[5], bo4=bp[6], bo5=bp[7], bo6=bp[8], Desi=bp[9];
    float bo_out = fe_bo[0];
    const float* cb = cell  + b*9;
    const float* rb = rcell + b*9;

    int k = blockIdx.x*256 + tid;            // NBONDS == gridDim.x*256 exactly
    int2 ij = ((const int2*)bdid)[k];
    int i = ij.x, j = ij.y;
    float dx0 = s_x[3*i+0]-s_x[3*j+0];
    float dx1 = s_x[3*i+1]-s_x[3*j+1];
    float dx2 = s_x[3*i+2]-s_x[3*j+2];
    // fractional coords, minimum image, back to cartesian
    float f0 = dx0*rb[0]+dx1*rb[3]+dx2*rb[6];
    float f1 = dx0*rb[1]+dx1*rb[4]+dx2*rb[7];
    float f2 = dx0*rb[2]+dx1*rb[5]+dx2*rb[8];
    f0 = (f0>0.5f)?f0-1.f:f0; f0 = (f0<-0.5f)?f0+1.f:f0;
    f1 = (f1>0.5f)?f1-1.f:f1; f1 = (f1<-0.5f)?f1+1.f:f1;
    f2 = (f2>0.5f)?f2-1.f:f2; f2 = (f2<-0.5f)?f2+1.f:f2;
    float v0 = f0*cb[0]+f1*cb[3]+f2*cb[6];
    float v1 = f0*cb[1]+f1*cb[4]+f2*cb[7];
    float v2 = f0*cb[2]+f1*cb[5]+f2*cb[8];
    float r = sqrtf(v0*v0+v1*v1+v2*v2);

    float eterm1 = (1.f+botol)*__expf(bo1*__powf(r/rosi, bo2));
    float eterm2 = __expf(bo3*__powf(r/ropi, bo4));
    float eterm3 = __expf(bo5*__powf(r/ropp, bo6));
    float tmax = 2.f*botol;
    float si = taperf_(eterm1, botol, tmax)*(eterm1-botol);
    float pi = taperf_(eterm2, botol, tmax)*eterm2;
    float pp = taperf_(eterm3, botol, tmax)*eterm3;

    // ---- MLP: 3 -> 8 -> (8x8)x5 -> 1, sigmoid everywhere ----
    float o[8];
    #pragma unroll
    for(int u=0;u<8;u++)
        o[u] = sigmoidf_(si*s_wi[u] + pi*s_wi[8+u] + pp*s_wi[16+u]);
    #pragma unroll
    for(int l=0;l<5;l++){
        const float4* wl = (const float4*)(s_w + (l<<6));
        const float*  bl = s_bb + (l<<3);
        float no[8];
        #pragma unroll
        for(int u=0;u<8;u++){
            float4 wa = wl[2*u], wb = wl[2*u+1];      // uniform ds_read_b128 x2
            float a0 = fmaf(o[0],wa.x, bl[u]);
            float a1 = o[1]*wa.y;
            a0 = fmaf(o[2],wa.z,a0); a1 = fmaf(o[3],wa.w,a1);
            a0 = fmaf(o[4],wb.x,a0); a1 = fmaf(o[5],wb.y,a1);
            a0 = fmaf(o[6],wb.z,a0); a1 = fmaf(o[7],wb.w,a1);
            no[u] = sigmoidf_(a0+a1);
        }
        #pragma unroll
        for(int u=0;u<8;u++) o[u]=no[u];
    }
    float4 woa = ((const float4*)s_wo)[0], wob = ((const float4*)s_wo)[1];
    float a0 = fmaf(o[0],woa.x, bo_out);
    float a1 = o[1]*woa.y;
    a0 = fmaf(o[2],woa.z,a0); a1 = fmaf(o[3],woa.w,a1);
    a0 = fmaf(o[4],wob.x,a0); a1 = fmaf(o[5],wob.y,a1);
    a0 = fmaf(o[6],wob.z,a0); a1 = fmaf(o[7],wob.w,a1);
    float esi = sigmoidf_(a0+a1);

    // per-atom scatter: first arrival on the (b,i,j) bit owns the pair
    {
        unsigned pidx = (unsigned)(i*NATOMS + j);
        unsigned old = atomicOr(&bits[(size_t)b*BITS_W + (pidx>>5)], 1u<<(pidx&31));
        if(((old>>(pidx&31)) & 1u) == 0u){
            float bop = si+pi+pp;
            float dpi = pi+pp;
            float* Db = Delta    + (size_t)b*NATOMS;
            float* Pb = Delta_pi + (size_t)b*NATOMS;
            float* Sb = SO       + (size_t)b*NATOMS;
            atomicAdd(&Db[i], bop); atomicAdd(&Db[j], bop);
            atomicAdd(&Pb[i], dpi); atomicAdd(&Pb[j], dpi);
            atomicAdd(&Sb[i], si);  atomicAdd(&Sb[j], si);
        }
    }

    // ebond partial: sum over ALL bonds (duplicates included)
    float ev = -Desi*esi;
    #pragma unroll
    for(int o2=32;o2>0;o2>>=1) ev += __shfl_down(ev, o2, 64);
    if((tid & 63) == 0) s_part[tid>>6] = ev;
    __syncthreads();
    if(tid==0) atomicAdd(&ebond_acc[b], s_part[0]+s_part[1]+s_part[2]+s_part[3]);

    // take a completion ticket for batch b. The barrier above drained this
    // block's vmcnt -> all its device-scope atomics are performed. No fence.
    __syncthreads();
    if(tid==0) s_rank = atomicAdd(&done[b], 1u);
    __syncthreads();
    if(s_rank != BPB-1) return;

    // ---- tail block (last to finish for this batch): atom phase ----
    float lp1=gp[0], ovun3=gp[1], ovun4=gp[2], ovun6=gp[3], ovun7=gp[4], ovun8=gp[5];
    float acc = 0.f;
    for(int n=tid; n<NATOMS; n+=256){
        int s = spec[n];
        const float* pa = sp_p + s*5;
        float val=pa[0], vale=pa[1], lp2=pa[2], ovun2=pa[3], ovun5=pa[4];
        size_t idx = (size_t)b*NATOMS + n;
        // agent-scope atomic loads: read through the coherent point, no stale L1
        float D   = __hip_atomic_load(&Delta[idx],    __ATOMIC_RELAXED, __HIP_MEMORY_SCOPE_AGENT);
        float Dpi = __hip_atomic_load(&Delta_pi[idx], __ATOMIC_RELAXED, __HIP_MEMORY_SCOPE_AGENT);
        float so  = __hip_atomic_load(&SO[idx],       __ATOMIC_RELAXED, __HIP_MEMORY_SCOPE_AGENT);

        float Nlp = 0.5f*(vale-val);
        float de  = 0.5f*(D-vale);
        float De  = fminf(ceilf(de), 0.f);          // -relu(-ceil(x)) == min(ceil(x),0)
        float t   = 1.f + de - De;
        float nlp = -De + __expf(-lp1*4.f*t*t);
        float Dlp = fmaxf(Nlp - nlp + 1.f, 0.f) - 1.f;
        float Elone = lp2*Dlp/(1.f+__expf(-75.f*Dlp));
        float dlp = D - val - Dlp/(1.f + ovun3*__expf(ovun4*Dpi));
        float denom = dlp + val;
        float otrm1 = 1.f/((denom!=0.f)?denom:1e-8f);
        float Eover = so*otrm1*dlp*sigmoidf_(-ovun2*dlp);
        float Eunder = -ovun5*(1.f-__expf(ovun6*dlp))*sigmoidf_(ovun2*dlp)
                       /(1.f + ovun7*__expf(ovun8*Dpi));
        acc += Elone + Eover + Eunder;
    }
    #pragma unroll
    for(int o2=32;o2>0;o2>>=1) acc += __shfl_down(acc, o2, 64);
    __syncthreads();                          // s_part reuse
    if((tid & 63) == 0) s_part[tid>>6] = acc;
    __syncthreads();
    if(tid==0){
        float eb = __hip_atomic_load(&ebond_acc[b], __ATOMIC_RELAXED, __HIP_MEMORY_SCOPE_AGENT);
        out[b] = eb + s_part[0]+s_part[1]+s_part[2]+s_part[3];   // sole writer
    }
}

extern "C" void kernel_launch(void* const* d_in, const int* in_sizes, int n_in,
                              void* d_out, int out_size, void* d_ws, size_t ws_size,
                              hipStream_t stream)
{
    const float* x     = (const float*)d_in[0];
    const float* cell  = (const float*)d_in[1];
    const float* rcell = (const float*)d_in[2];
    const float* sp_p  = (const float*)d_in[3];
    const float* gp    = (const float*)d_in[4];
    const float* bp    = (const float*)d_in[5];
    const float* fe_wi = (const float*)d_in[6];
    const float* fe_w  = (const float*)d_in[7];
    const float* fe_b  = (const float*)d_in[8];
    const float* fe_wo = (const float*)d_in[9];
    const float* fe_bo = (const float*)d_in[10];
    const int*   bdid  = (const int*)d_in[11];
    const int*   spec  = (const int*)d_in[12];
    float* out = (float*)d_out;

    // ws layout (contiguous, one memset):
    // Delta | Delta_pi | SO | ebond_acc | done | ownership bits
    float* Delta     = (float*)d_ws;
    float* Delta_pi  = Delta + BATCH*NATOMS;
    float* SO        = Delta_pi + BATCH*NATOMS;
    float* ebond_acc = SO + BATCH*NATOMS;
    unsigned* done   = (unsigned*)(ebond_acc + BATCH);
    unsigned* bits   = done + BATCH;

    size_t zbytes = (size_t)(3*BATCH*NATOMS + BATCH)*sizeof(float)
                  + (size_t)BATCH*sizeof(unsigned)
                  + (size_t)BATCH*BITS_W*sizeof(unsigned);
    hipMemsetAsync(d_ws, 0, zbytes, stream);

    fused_kernel<<<dim3(BPB, BATCH), 256, 0, stream>>>(
        x, cell, rcell, sp_p, gp, bp, fe_wi, fe_w, fe_b, fe_wo, fe_bo,
        bdid, spec, Delta, Delta_pi, SO, ebond_acc, done, bits, out);
}